// Round 1
// baseline (74.066 us; speedup 1.0000x reference)
//
#include <hip/hip_runtime.h>

// EVI fused kernel: ev-projection -> 20-proto evidence scan -> normalize -> back-projection.
// x: (B=2, 64, 64, 64, 64) fp32, out: (2, 64, 64, 64, 64) fp32. Memory-bound (~268 MB traffic).

constexpr int kInCh   = 64;
constexpr int kCls    = 4;
constexpr int kProto  = 20;
constexpr int kB      = 2;
constexpr long kSpatial = 64L * 64L * 64L;   // 262144, D contiguous
constexpr int kVec    = 4;                    // float4 voxels per thread

__global__ __launch_bounds__(256) void evi_fused_kernel(
    const float* __restrict__ x,
    const float* __restrict__ w_to,    // (CLS, IN_CH)
    const float* __restrict__ b_to,    // (CLS,)
    const float* __restrict__ w_from,  // (IN_CH, CLS)
    const float* __restrict__ b_from,  // (IN_CH,)
    const float* __restrict__ Wm,      // (PROTO, CLS)
    const float* __restrict__ BETA,    // (PROTO, CLS)
    const float* __restrict__ alpha,   // (PROTO, 1)
    const float* __restrict__ gamma,   // (PROTO, 1)
    float* __restrict__ out)
{
    __shared__ float s_wt[kCls * kInCh];   // w_to[o][c]
    __shared__ float s_wf[kInCh * kCls];   // w_from[i][c]
    __shared__ float s_bf[kInCh];
    __shared__ float s_bto[kCls];
    __shared__ float s_W[kProto][kCls];
    __shared__ float s_U[kProto][kCls];
    __shared__ float s_ap[kProto];
    __shared__ float s_g2[kProto];

    const int t = threadIdx.x;

    // ---- stage weights / per-proto params into LDS (once per block) ----
    s_wt[t] = w_to[t];
    s_wf[t] = w_from[t];
    if (t < kInCh) s_bf[t] = b_from[t];
    if (t < kCls)  s_bto[t] = b_to[t];
    if (t < kProto) {
        float bsq[kCls];
        float sum = 0.f;
        #pragma unroll
        for (int c = 0; c < kCls; ++c) {
            const float bb = BETA[t * kCls + c];
            bsq[c] = bb * bb;
            sum += bsq[c];
        }
        const float inv = 1.0f / sum;
        #pragma unroll
        for (int c = 0; c < kCls; ++c) {
            s_U[t][c] = bsq[c] * inv;
            s_W[t][c] = Wm[t * kCls + c];
        }
        s_ap[t] = 0.99f / (1.0f + expf(-alpha[t]));
        const float g = gamma[t];
        s_g2[t] = g * g;
    }
    __syncthreads();

    const int S4 = (int)(kSpatial / kVec);               // 65536
    const int idx = blockIdx.x * blockDim.x + t;
    if (idx >= kB * S4) return;
    const int b = idx / S4;
    const int r = idx - b * S4;
    const size_t base = (size_t)b * kInCh * kSpatial + (size_t)r * kVec;

    // ---- ev = w_to . x + b_to ----
    float ev[kCls][kVec];
    #pragma unroll
    for (int o = 0; o < kCls; ++o)
        #pragma unroll
        for (int v = 0; v < kVec; ++v) ev[o][v] = s_bto[o];

    #pragma unroll 8
    for (int c = 0; c < kInCh; ++c) {
        const float4 xv = *reinterpret_cast<const float4*>(x + base + (size_t)c * kSpatial);
        #pragma unroll
        for (int o = 0; o < kCls; ++o) {
            const float w = s_wt[o * kInCh + c];
            ev[o][0] += xv.x * w;
            ev[o][1] += xv.y * w;
            ev[o][2] += xv.z * w;
            ev[o][3] += xv.w * w;
        }
    }

    // ---- evidence scan over 20 prototypes ----
    float mkc[kCls][kVec];
    float mk5[kVec];
    #pragma unroll
    for (int v = 0; v < kVec; ++v) {
        mk5[v] = 1.0f;
        #pragma unroll
        for (int c = 0; c < kCls; ++c) mkc[c][v] = 0.0f;
    }

    for (int k = 0; k < kProto; ++k) {
        float Wk[kCls], Uk[kCls];
        #pragma unroll
        for (int c = 0; c < kCls; ++c) { Wk[c] = s_W[k][c]; Uk[c] = s_U[k][c]; }
        const float ap = s_ap[k];
        const float g2 = s_g2[k];
        #pragma unroll
        for (int v = 0; v < kVec; ++v) {
            float d = 0.0f;
            #pragma unroll
            for (int c = 0; c < kCls; ++c) {
                const float df = ev[c][v] - Wk[c];
                d += df * df;
            }
            d *= 0.5f;
            const float s  = ap * __expf(-g2 * d);
            const float m5 = 1.0f - s;
            const float old5 = mk5[v];
            #pragma unroll
            for (int c = 0; c < kCls; ++c) {
                const float mc = Uk[c] * s;
                mkc[c][v] = mkc[c][v] * (mc + m5) + mc * old5;
            }
            mk5[v] = old5 * m5;
        }
    }

    // ---- normalize: evid[c] = (mkc[c] + mk5) / K ----
    float evid[kCls][kVec];
    #pragma unroll
    for (int v = 0; v < kVec; ++v) {
        float K = mk5[v];
        #pragma unroll
        for (int c = 0; c < kCls; ++c) K += mkc[c][v];
        const float inv = 1.0f / K;
        #pragma unroll
        for (int c = 0; c < kCls; ++c) evid[c][v] = (mkc[c][v] + mk5[v]) * inv;
    }

    // ---- out = w_from . evid + b_from ----
    #pragma unroll 8
    for (int o = 0; o < kInCh; ++o) {
        const float w0 = s_wf[o * kCls + 0];
        const float w1 = s_wf[o * kCls + 1];
        const float w2 = s_wf[o * kCls + 2];
        const float w3 = s_wf[o * kCls + 3];
        float4 acc;
        acc.x = s_bf[o] + evid[0][0]*w0 + evid[1][0]*w1 + evid[2][0]*w2 + evid[3][0]*w3;
        acc.y = s_bf[o] + evid[0][1]*w0 + evid[1][1]*w1 + evid[2][1]*w2 + evid[3][1]*w3;
        acc.z = s_bf[o] + evid[0][2]*w0 + evid[1][2]*w1 + evid[2][2]*w2 + evid[3][2]*w3;
        acc.w = s_bf[o] + evid[0][3]*w0 + evid[1][3]*w1 + evid[2][3]*w2 + evid[3][3]*w3;
        *reinterpret_cast<float4*>(out + base + (size_t)o * kSpatial) = acc;
    }
}

extern "C" void kernel_launch(void* const* d_in, const int* in_sizes, int n_in,
                              void* d_out, int out_size, void* d_ws, size_t ws_size,
                              hipStream_t stream) {
    const float* x      = (const float*)d_in[0];
    const float* w_to   = (const float*)d_in[1];
    const float* b_to   = (const float*)d_in[2];
    const float* w_from = (const float*)d_in[3];
    const float* b_from = (const float*)d_in[4];
    const float* Wm     = (const float*)d_in[5];
    const float* BETA   = (const float*)d_in[6];
    const float* alpha  = (const float*)d_in[7];
    const float* gamma  = (const float*)d_in[8];
    float* out = (float*)d_out;

    const int total = (int)(kB * kSpatial / kVec);   // 131072 threads
    const int block = 256;
    const int grid = (total + block - 1) / block;    // 512 blocks
    evi_fused_kernel<<<grid, block, 0, stream>>>(x, w_to, b_to, w_from, b_from,
                                                 Wm, BETA, alpha, gamma, out);
}

// Round 2
// 52.045 us; speedup vs baseline: 1.4231x; 1.4231x over previous
//
#include <hip/hip_runtime.h>

// EVI fused kernel, round 2: channel-split across 4 lanes per voxel-group.
// - 4 threads co-own one float4 voxel group; each loads/stores 16 of 64 channels.
// - ev reduced across chunks via __shfl_xor(16/32); scan recomputed per chunk (cheap VALU).
// - Non-temporal stores keep `out` from evicting x (134 MB) out of the 256 MB L3.
// Occupancy: 2048 blocks x 256 thr = 8192 waves -> up to 32 waves/CU (was 8).

constexpr int kInCh    = 64;
constexpr int kCls     = 4;
constexpr int kProto   = 20;
constexpr long kSpatial = 64L * 64L * 64L;   // 262144, D contiguous
constexpr int kVec     = 4;                   // float4 voxels per group
constexpr int kChunk   = 16;                  // channels per thread

typedef float f32x4 __attribute__((ext_vector_type(4)));

__global__ __launch_bounds__(256, 4) void evi_fused_kernel(
    const float* __restrict__ x,
    const float* __restrict__ w_to,    // (CLS, IN_CH)
    const float* __restrict__ b_to,    // (CLS,)
    const float* __restrict__ w_from,  // (IN_CH, CLS)
    const float* __restrict__ b_from,  // (IN_CH,)
    const float* __restrict__ Wm,      // (PROTO, CLS)
    const float* __restrict__ BETA,    // (PROTO, CLS)
    const float* __restrict__ alpha,   // (PROTO, 1)
    const float* __restrict__ gamma,   // (PROTO, 1)
    float* __restrict__ out)
{
    __shared__ float s_wt[kCls * kInCh];   // w_to[o][c]
    __shared__ float s_wf[kInCh * kCls];   // w_from[i][c]
    __shared__ float s_bf[kInCh];
    __shared__ float s_bto[kCls];
    __shared__ float s_W[kProto][kCls];
    __shared__ float s_U[kProto][kCls];
    __shared__ float s_ap[kProto];
    __shared__ float s_g2[kProto];

    const int t = threadIdx.x;

    // ---- stage weights / per-proto params into LDS (once per block) ----
    s_wt[t] = w_to[t];
    s_wf[t] = w_from[t];
    if (t < kInCh) s_bf[t] = b_from[t];
    if (t < kCls)  s_bto[t] = b_to[t];
    if (t < kProto) {
        float bsq[kCls];
        float sum = 0.f;
        #pragma unroll
        for (int c = 0; c < kCls; ++c) {
            const float bb = BETA[t * kCls + c];
            bsq[c] = bb * bb;
            sum += bsq[c];
        }
        const float inv = 1.0f / sum;
        #pragma unroll
        for (int c = 0; c < kCls; ++c) {
            s_U[t][c] = bsq[c] * inv;
            s_W[t][c] = Wm[t * kCls + c];
        }
        s_ap[t] = 0.99f / (1.0f + expf(-alpha[t]));
        const float g = gamma[t];
        s_g2[t] = g * g;
    }
    __syncthreads();

    // ---- lane decomposition ----
    const int tid   = blockIdx.x * blockDim.x + t;
    const int wave  = tid >> 6;
    const int lane  = tid & 63;
    const int chunk = lane >> 4;           // 0..3 -> channels [chunk*16, chunk*16+16)
    const int vg    = wave * 16 + (lane & 15);   // voxel-group id, [0, 131072)

    const int vgPerBatch = (int)(kSpatial / kVec);   // 65536
    const int b = vg >> 16;                          // vg / 65536
    const int r = vg & (vgPerBatch - 1);
    const size_t base = (size_t)b * kInCh * kSpatial + (size_t)r * kVec;
    const int c0 = chunk * kChunk;

    // ---- partial ev over this thread's 16 channels ----
    float ev[kCls][kVec];
    #pragma unroll
    for (int o = 0; o < kCls; ++o)
        #pragma unroll
        for (int v = 0; v < kVec; ++v) ev[o][v] = 0.0f;

    #pragma unroll
    for (int j = 0; j < kChunk; ++j) {
        const int c = c0 + j;
        const f32x4 xv = *reinterpret_cast<const f32x4*>(x + base + (size_t)c * kSpatial);
        #pragma unroll
        for (int o = 0; o < kCls; ++o) {
            const float w = s_wt[o * kInCh + c];
            ev[o][0] += xv.x * w;
            ev[o][1] += xv.y * w;
            ev[o][2] += xv.z * w;
            ev[o][3] += xv.w * w;
        }
    }

    // ---- cross-chunk reduce (lanes l, l+16, l+32, l+48 share a voxel group) ----
    #pragma unroll
    for (int o = 0; o < kCls; ++o)
        #pragma unroll
        for (int v = 0; v < kVec; ++v) {
            float e = ev[o][v];
            e += __shfl_xor(e, 16, 64);
            e += __shfl_xor(e, 32, 64);
            ev[o][v] = e + s_bto[o];
        }

    // ---- evidence scan over 20 prototypes (redundant across chunks; pure VALU) ----
    float mkc[kCls][kVec];
    float mk5[kVec];
    #pragma unroll
    for (int v = 0; v < kVec; ++v) {
        mk5[v] = 1.0f;
        #pragma unroll
        for (int c = 0; c < kCls; ++c) mkc[c][v] = 0.0f;
    }

    for (int k = 0; k < kProto; ++k) {
        float Wk[kCls], Uk[kCls];
        #pragma unroll
        for (int c = 0; c < kCls; ++c) { Wk[c] = s_W[k][c]; Uk[c] = s_U[k][c]; }
        const float ap = s_ap[k];
        const float g2 = s_g2[k];
        #pragma unroll
        for (int v = 0; v < kVec; ++v) {
            float d = 0.0f;
            #pragma unroll
            for (int c = 0; c < kCls; ++c) {
                const float df = ev[c][v] - Wk[c];
                d += df * df;
            }
            d *= 0.5f;
            const float s  = ap * __expf(-g2 * d);
            const float m5 = 1.0f - s;
            const float old5 = mk5[v];
            #pragma unroll
            for (int c = 0; c < kCls; ++c) {
                const float mc = Uk[c] * s;
                mkc[c][v] = mkc[c][v] * (mc + m5) + mc * old5;
            }
            mk5[v] = old5 * m5;
        }
    }

    // ---- normalize in place: mkc[c] <- (mkc[c] + mk5) / K ----
    #pragma unroll
    for (int v = 0; v < kVec; ++v) {
        float K = mk5[v];
        #pragma unroll
        for (int c = 0; c < kCls; ++c) K += mkc[c][v];
        const float inv = 1.0f / K;
        #pragma unroll
        for (int c = 0; c < kCls; ++c) mkc[c][v] = (mkc[c][v] + mk5[v]) * inv;
    }

    // ---- back-projection: this thread's 16 output channels, nt stores ----
    #pragma unroll
    for (int j = 0; j < kChunk; ++j) {
        const int o = c0 + j;
        const float w0 = s_wf[o * kCls + 0];
        const float w1 = s_wf[o * kCls + 1];
        const float w2 = s_wf[o * kCls + 2];
        const float w3 = s_wf[o * kCls + 3];
        const float bo = s_bf[o];
        f32x4 acc;
        acc.x = bo + mkc[0][0]*w0 + mkc[1][0]*w1 + mkc[2][0]*w2 + mkc[3][0]*w3;
        acc.y = bo + mkc[0][1]*w0 + mkc[1][1]*w1 + mkc[2][1]*w2 + mkc[3][1]*w3;
        acc.z = bo + mkc[0][2]*w0 + mkc[1][2]*w1 + mkc[2][2]*w2 + mkc[3][2]*w3;
        acc.w = bo + mkc[0][3]*w0 + mkc[1][3]*w1 + mkc[2][3]*w2 + mkc[3][3]*w3;
        __builtin_nontemporal_store(acc, reinterpret_cast<f32x4*>(out + base + (size_t)o * kSpatial));
    }
}

extern "C" void kernel_launch(void* const* d_in, const int* in_sizes, int n_in,
                              void* d_out, int out_size, void* d_ws, size_t ws_size,
                              hipStream_t stream) {
    const float* x      = (const float*)d_in[0];
    const float* w_to   = (const float*)d_in[1];
    const float* b_to   = (const float*)d_in[2];
    const float* w_from = (const float*)d_in[3];
    const float* b_from = (const float*)d_in[4];
    const float* Wm     = (const float*)d_in[5];
    const float* BETA   = (const float*)d_in[6];
    const float* alpha  = (const float*)d_in[7];
    const float* gamma  = (const float*)d_in[8];
    float* out = (float*)d_out;

    // 131072 voxel-groups x 4 chunk-threads = 524288 threads
    const int block = 256;
    const int grid  = 2048;
    evi_fused_kernel<<<grid, block, 0, stream>>>(x, w_to, b_to, w_from, b_from,
                                                 Wm, BETA, alpha, gamma, out);
}

// Round 3
// 51.419 us; speedup vs baseline: 1.4404x; 1.0122x over previous
//
#include <hip/hip_runtime.h>

// EVI fused kernel, round 3: scan de-duplication across chunk-threads.
// - 4 threads co-own one float4 voxel group; each loads/stores 16 of 64 channels.
// - ev reduced across chunks via __shfl_xor(16/32).
// - NEW: each chunk-thread runs the 20-proto scan for ONE vec element (v = chunk),
//   then evid is redistributed with 16 __shfl's. Cuts scan VALU work 4x.
// - Non-temporal stores keep `out` from evicting x out of the 256 MB L3.

constexpr int kInCh    = 64;
constexpr int kCls     = 4;
constexpr int kProto   = 20;
constexpr long kSpatial = 64L * 64L * 64L;   // 262144, D contiguous
constexpr int kVec     = 4;                   // float4 voxels per group
constexpr int kChunk   = 16;                  // channels per thread

typedef float f32x4 __attribute__((ext_vector_type(4)));

__global__ __launch_bounds__(256, 4) void evi_fused_kernel(
    const float* __restrict__ x,
    const float* __restrict__ w_to,    // (CLS, IN_CH)
    const float* __restrict__ b_to,    // (CLS,)
    const float* __restrict__ w_from,  // (IN_CH, CLS)
    const float* __restrict__ b_from,  // (IN_CH,)
    const float* __restrict__ Wm,      // (PROTO, CLS)
    const float* __restrict__ BETA,    // (PROTO, CLS)
    const float* __restrict__ alpha,   // (PROTO, 1)
    const float* __restrict__ gamma,   // (PROTO, 1)
    float* __restrict__ out)
{
    __shared__ float s_wt[kCls * kInCh];   // w_to[o][c]
    __shared__ float s_wf[kInCh * kCls];   // w_from[i][c]
    __shared__ float s_bf[kInCh];
    __shared__ float s_bto[kCls];
    __shared__ float s_W[kProto][kCls];
    __shared__ float s_U[kProto][kCls];
    __shared__ float s_ap[kProto];
    __shared__ float s_g2[kProto];

    const int t = threadIdx.x;

    // ---- stage weights / per-proto params into LDS (once per block) ----
    s_wt[t] = w_to[t];
    s_wf[t] = w_from[t];
    if (t < kInCh) s_bf[t] = b_from[t];
    if (t < kCls)  s_bto[t] = b_to[t];
    if (t < kProto) {
        float bsq[kCls];
        float sum = 0.f;
        #pragma unroll
        for (int c = 0; c < kCls; ++c) {
            const float bb = BETA[t * kCls + c];
            bsq[c] = bb * bb;
            sum += bsq[c];
        }
        const float inv = 1.0f / sum;
        #pragma unroll
        for (int c = 0; c < kCls; ++c) {
            s_U[t][c] = bsq[c] * inv;
            s_W[t][c] = Wm[t * kCls + c];
        }
        s_ap[t] = 0.99f / (1.0f + expf(-alpha[t]));
        const float g = gamma[t];
        s_g2[t] = g * g;
    }
    __syncthreads();

    // ---- lane decomposition ----
    const int tid   = blockIdx.x * blockDim.x + t;
    const int wave  = tid >> 6;
    const int lane  = tid & 63;
    const int chunk = lane >> 4;                 // 0..3 -> channels [chunk*16, chunk*16+16)
    const int vg    = wave * 16 + (lane & 15);   // voxel-group id, [0, 131072)

    const int vgPerBatch = (int)(kSpatial / kVec);   // 65536
    const int b = vg >> 16;
    const int r = vg & (vgPerBatch - 1);
    const size_t base = (size_t)b * kInCh * kSpatial + (size_t)r * kVec;
    const int c0 = chunk * kChunk;

    // ---- partial ev over this thread's 16 channels ----
    float ev[kCls][kVec];
    #pragma unroll
    for (int o = 0; o < kCls; ++o)
        #pragma unroll
        for (int v = 0; v < kVec; ++v) ev[o][v] = 0.0f;

    #pragma unroll
    for (int j = 0; j < kChunk; ++j) {
        const int c = c0 + j;
        const f32x4 xv = *reinterpret_cast<const f32x4*>(x + base + (size_t)c * kSpatial);
        #pragma unroll
        for (int o = 0; o < kCls; ++o) {
            const float w = s_wt[o * kInCh + c];
            ev[o][0] += xv.x * w;
            ev[o][1] += xv.y * w;
            ev[o][2] += xv.z * w;
            ev[o][3] += xv.w * w;
        }
    }

    // ---- cross-chunk reduce (lanes l, l+16, l+32, l+48 share a voxel group) ----
    #pragma unroll
    for (int o = 0; o < kCls; ++o)
        #pragma unroll
        for (int v = 0; v < kVec; ++v) {
            float e = ev[o][v];
            e += __shfl_xor(e, 16, 64);
            e += __shfl_xor(e, 32, 64);
            ev[o][v] = e + s_bto[o];
        }

    // ---- select this thread's vec element (v = chunk) WITHOUT runtime indexing ----
    float evs[kCls];
    #pragma unroll
    for (int c = 0; c < kCls; ++c) {
        float e = ev[c][0];
        e = (chunk == 1) ? ev[c][1] : e;
        e = (chunk == 2) ? ev[c][2] : e;
        e = (chunk == 3) ? ev[c][3] : e;
        evs[c] = e;
    }

    // ---- evidence scan over 20 prototypes (ONE vec element per thread) ----
    float mkc[kCls];
    float mk5 = 1.0f;
    #pragma unroll
    for (int c = 0; c < kCls; ++c) mkc[c] = 0.0f;

    for (int k = 0; k < kProto; ++k) {
        float d = 0.0f;
        #pragma unroll
        for (int c = 0; c < kCls; ++c) {
            const float df = evs[c] - s_W[k][c];
            d += df * df;
        }
        d *= 0.5f;
        const float s  = s_ap[k] * __expf(-s_g2[k] * d);
        const float m5 = 1.0f - s;
        const float old5 = mk5;
        #pragma unroll
        for (int c = 0; c < kCls; ++c) {
            const float mc = s_U[k][c] * s;
            mkc[c] = mkc[c] * (mc + m5) + mc * old5;
        }
        mk5 = old5 * m5;
    }

    // ---- normalize: evid_s[c] = (mkc[c] + mk5) / K ----
    float K = mk5;
    #pragma unroll
    for (int c = 0; c < kCls; ++c) K += mkc[c];
    const float invK = 1.0f / K;
    float evid_s[kCls];
    #pragma unroll
    for (int c = 0; c < kCls; ++c) evid_s[c] = (mkc[c] + mk5) * invK;

    // ---- redistribute: evid[c][v] comes from chunk-thread v of this voxel group ----
    float evid[kCls][kVec];
    const int laneBase = lane & 15;
    #pragma unroll
    for (int c = 0; c < kCls; ++c) {
        #pragma unroll
        for (int v = 0; v < kVec; ++v)
            evid[c][v] = __shfl(evid_s[c], laneBase + v * 16, 64);
    }

    // ---- back-projection: this thread's 16 output channels, nt stores ----
    #pragma unroll
    for (int j = 0; j < kChunk; ++j) {
        const int o = c0 + j;
        const float w0 = s_wf[o * kCls + 0];
        const float w1 = s_wf[o * kCls + 1];
        const float w2 = s_wf[o * kCls + 2];
        const float w3 = s_wf[o * kCls + 3];
        const float bo = s_bf[o];
        f32x4 acc;
        acc.x = bo + evid[0][0]*w0 + evid[1][0]*w1 + evid[2][0]*w2 + evid[3][0]*w3;
        acc.y = bo + evid[0][1]*w0 + evid[1][1]*w1 + evid[2][1]*w2 + evid[3][1]*w3;
        acc.z = bo + evid[0][2]*w0 + evid[1][2]*w1 + evid[2][2]*w2 + evid[3][2]*w3;
        acc.w = bo + evid[0][3]*w0 + evid[1][3]*w1 + evid[2][3]*w2 + evid[3][3]*w3;
        __builtin_nontemporal_store(acc, reinterpret_cast<f32x4*>(out + base + (size_t)o * kSpatial));
    }
}

extern "C" void kernel_launch(void* const* d_in, const int* in_sizes, int n_in,
                              void* d_out, int out_size, void* d_ws, size_t ws_size,
                              hipStream_t stream) {
    const float* x      = (const float*)d_in[0];
    const float* w_to   = (const float*)d_in[1];
    const float* b_to   = (const float*)d_in[2];
    const float* w_from = (const float*)d_in[3];
    const float* b_from = (const float*)d_in[4];
    const float* Wm     = (const float*)d_in[5];
    const float* BETA   = (const float*)d_in[6];
    const float* alpha  = (const float*)d_in[7];
    const float* gamma  = (const float*)d_in[8];
    float* out = (float*)d_out;

    // 131072 voxel-groups x 4 chunk-threads = 524288 threads
    const int block = 256;
    const int grid  = 2048;
    evi_fused_kernel<<<grid, block, 0, stream>>>(x, w_to, b_to, w_from, b_from,
                                                 Wm, BETA, alpha, gamma, out);
}